// Round 3
// baseline (388.789 us; speedup 1.0000x reference)
//
#include <hip/hip_runtime.h>

// Problem constants (from reference)
#define DCOLS 32        // dist/angle columns
#define WCOLS 32        // idx_t/index_t columns
#define NUM_CLASSES 22
#define ONEHOT_COLS (NUM_CLASSES * WCOLS)       // 704
#define OUT_COLS (ONEHOT_COLS + WCOLS + WCOLS)  // 768

// native clang vector type
typedef float vfloat4 __attribute__((ext_vector_type(4)));

// ---------------------------------------------------------------------------
// Min/max encoding (seeded by an 8-byte hipMemsetAsync of 0xFF):
//   ws[0] (uint): running MIN of bits(-v).  ws[1] (int): running MAX of bits(v).
// Recover: dmin = -as_float(ws[0]);  dmax = as_float(ws[1]).

// ---------------------------------------------------------------------------
// Kernel 1: global min/max over the gathered dist_t[h,w] values.
__global__ __launch_bounds__(256) void minmax_kernel(
    const float* __restrict__ dist,
    const int*   __restrict__ index_t,
    const int*   __restrict__ index_h,
    unsigned*    __restrict__ ws,
    int total4)  // total4 = H * WCOLS / 4
{
    float vmin = __int_as_float(0x7f800000);  // +inf
    float vmax = 0.0f;
    const int stride = gridDim.x * blockDim.x;
    for (int i4 = blockIdx.x * blockDim.x + threadIdx.x; i4 < total4; i4 += stride) {
        const int4 it = reinterpret_cast<const int4*>(index_t)[i4];
        const int  h  = i4 >> 3;              // (i4*4) >> 5
        const int  row = index_h[h] * DCOLS;  // index_h cacheline-broadcast
        float v0 = 0.0f, v1 = 0.0f, v2 = 0.0f, v3 = 0.0f;
        if (it.x < DCOLS) v0 = dist[row + it.x];
        if (it.y < DCOLS) v1 = dist[row + it.y];
        if (it.z < DCOLS) v2 = dist[row + it.z];
        if (it.w < DCOLS) v3 = dist[row + it.w];
        vmin = fminf(fminf(fminf(vmin, v0), fminf(v1, v2)), v3);
        vmax = fmaxf(fmaxf(fmaxf(vmax, v0), fmaxf(v1, v2)), v3);
    }
    // wave-64 shuffle reduce (uniform execution: loop reconverges before this)
    #pragma unroll
    for (int off = 32; off > 0; off >>= 1) {
        vmin = fminf(vmin, __shfl_down(vmin, off, 64));
        vmax = fmaxf(vmax, __shfl_down(vmax, off, 64));
    }
    __shared__ float smin[4], smax[4];
    const int lane = threadIdx.x & 63;
    const int wave = threadIdx.x >> 6;
    if (lane == 0) { smin[wave] = vmin; smax[wave] = vmax; }
    __syncthreads();
    if (threadIdx.x == 0) {
        float m = smin[0], M = smax[0];
        #pragma unroll
        for (int k = 1; k < 4; ++k) { m = fminf(m, smin[k]); M = fmaxf(M, smax[k]); }
        atomicMin(ws,             __float_as_uint(-m));
        atomicMax((int*)(ws + 1), __float_as_int(M));
    }
}

// ---------------------------------------------------------------------------
// Kernel 2: wave-per-row, barrier-free, LDS-free.
//  - One wave64 owns one output row h. Lanes 0..31 gather+normalize dist,
//    lanes 32..63 gather angle; all lanes hold idx_t for their column.
//  - ROUND 3 FIX: every __shfl is issued at a WAVE-UNIFORM point. ds_bpermute
//    does NOT supply data from EXEC=0 source lanes — round 2 called __shfl
//    inside lane-divergent branches in the mixed s=2 quarter and read
//    undefined data. Now the store-loop body is branch-free: shuffles are
//    unconditional, selection is via ternaries.
__global__ __launch_bounds__(256) void fill_kernel(
    const float* __restrict__ dist,
    const float* __restrict__ angle,
    const int*   __restrict__ idx_t,
    const int*   __restrict__ index_t,
    const int*   __restrict__ index_h,
    const unsigned* __restrict__ ws,
    float*       __restrict__ out,
    int H)
{
    const int wave = threadIdx.x >> 6;           // 0..3
    const int lane = threadIdx.x & 63;
    const int h    = blockIdx.x * 4 + wave;      // one row per wave
    if (h >= H) return;                          // wave-uniform exit

    const float dmin = -__uint_as_float(ws[0]);
    const float dmax =  __uint_as_float(ws[1]);
    const float inv  = 1.0f / (dmax - dmin);

    const int c    = lane & 31;
    const int idxv = idx_t[h * WCOLS + c];       // duplicated across half-waves
    const int it   = index_t[h * WCOLS + c];
    const int base = index_h[h] * DCOLS;

    float g = 0.0f;                              // lanes 0..31: normalized dist
    if (lane < 32) {                             // lanes 32..63: raw angle
        if (it < DCOLS) g = dist[base + it];
        g = (g - dmin) * inv;                    // normalize in source lane
    } else {
        if (it < DCOLS) g = angle[base + it];
    }
    // divergence closed; everything below is wave-uniform control flow

    float* orow = out + (size_t)h * OUT_COLS;

    // s = 0,1 : columns 0..511, statically all one-hot
    #pragma unroll
    for (int s = 0; s < 2; ++s) {
        vfloat4 v4;
        #pragma unroll
        for (int k = 0; k < 4; ++k) {
            const int j  = s * 256 + lane * 4 + k;   // < 512 < ONEHOT_COLS
            const int w  = j / NUM_CLASSES;          // magic-mul div by 22
            const int cc = j - w * NUM_CLASSES;
            v4[k] = (__shfl(idxv, w, 64) == cc) ? 1.0f : 0.0f;  // uniform exec
        }
        *reinterpret_cast<vfloat4*>(orow + s * 256 + lane * 4) = v4;
    }

    // s = 2 : columns 512..767, mixes one-hot / dist / angle across lanes.
    // Branch-free: unconditional shuffles, ternary select.
    {
        vfloat4 v4;
        #pragma unroll
        for (int k = 0; k < 4; ++k) {
            const int  j    = 512 + lane * 4 + k;
            const bool isOH = (j < ONEHOT_COLS);
            const int  w    = isOH ? (j / NUM_CLASSES) : 0;
            const int  cc   = j - w * NUM_CLASSES;
            const int  gsrc = isOH ? 0
                             : (j < ONEHOT_COLS + WCOLS)
                                 ? (j - ONEHOT_COLS)                 // dist lane 0..31
                                 : (j - (ONEHOT_COLS + WCOLS) + 32); // angle lane 32..63
            const int   ohv = __shfl(idxv, w, 64);   // all 64 lanes execute
            const float gv  = __shfl(g, gsrc, 64);   // all 64 lanes execute
            v4[k] = isOH ? ((ohv == cc) ? 1.0f : 0.0f) : gv;
        }
        *reinterpret_cast<vfloat4*>(orow + 512 + lane * 4) = v4;
    }
}

// ---------------------------------------------------------------------------
extern "C" void kernel_launch(void* const* d_in, const int* in_sizes, int n_in,
                              void* d_out, int out_size, void* d_ws, size_t ws_size,
                              hipStream_t stream) {
    const float* dist    = (const float*)d_in[0];
    const float* angle   = (const float*)d_in[1];
    const int*   idx_t   = (const int*)d_in[2];
    const int*   index_t = (const int*)d_in[3];
    const int*   index_h = (const int*)d_in[4];
    float*       out     = (float*)d_out;
    unsigned*    ws      = (unsigned*)d_ws;

    const int H      = in_sizes[4];           // index_h has H elements
    const int total4 = (H * WCOLS) / 4;       // H*32 always divisible by 4

    // Seed both min/max accumulators with 0xFFFFFFFF (see encoding above).
    (void)hipMemsetAsync(ws, 0xFF, 8, stream);

    hipLaunchKernelGGL(minmax_kernel, dim3(1024), dim3(256), 0, stream,
                       dist, index_t, index_h, ws, total4);

    const int fill_blocks = (H + 3) / 4;      // one row per wave, 4 waves/block
    hipLaunchKernelGGL(fill_kernel, dim3(fill_blocks), dim3(256), 0, stream,
                       dist, angle, idx_t, index_t, index_h, ws, out, H);
}

// Round 4
// 371.958 us; speedup vs baseline: 1.0452x; 1.0452x over previous
//
#include <hip/hip_runtime.h>

// Problem constants (from reference)
#define DCOLS 32        // dist/angle columns
#define WCOLS 32        // idx_t/index_t columns
#define NUM_CLASSES 22
#define ONEHOT_COLS (NUM_CLASSES * WCOLS)       // 704
#define OUT_COLS (ONEHOT_COLS + WCOLS + WCOLS)  // 768
#define ROWS_PER_BLOCK 8                        // 8 rows x 32 cols = 256 gather threads

// native clang vector type — __builtin_nontemporal_store requires it
typedef float vfloat4 __attribute__((ext_vector_type(4)));

// ---------------------------------------------------------------------------
// BEST-MEASURED VARIANT (372.3 us this session, 373.5 us prior session).
// Round 1 (cached stores): 378.8. Round 3 (wave-per-row, no LDS/barriers):
// 388.8. Three structurally different fills within ~4% => fill_kernel is a
// minor fraction of the timed region; dominated by the harness's 1.23 GB
// poison fill (~195 us) + reset/restore dispatches. Reverted to best.
// ---------------------------------------------------------------------------
// Min/max encoding (seeded by an 8-byte hipMemsetAsync of 0xFF):
//   ws[0] (uint): running MIN of bits(-v).  v>=0 -> -v is a negative float;
//     for negative floats, smaller uint bits == larger float == smaller v.
//     So uint-min of bits(-v) tracks min(v).  Seed 0xFFFFFFFF >= everything.
//   ws[1] (int):  running MAX of bits(v).   v>=0 -> bits order == float order.
//     Seed 0xFFFFFFFF == -1 <= everything.
// Recover: dmin = -as_float(ws[0]);  dmax = as_float(ws[1]).

// ---------------------------------------------------------------------------
// Kernel 1: global min/max over the gathered dist_t[h,w] values.
// int4-vectorized: 4 consecutive elements share the same h (32 % 4 == 0).
__global__ __launch_bounds__(256) void minmax_kernel(
    const float* __restrict__ dist,
    const int*   __restrict__ index_t,
    const int*   __restrict__ index_h,
    unsigned*    __restrict__ ws,
    int total4)  // total4 = H * WCOLS / 4
{
    float vmin = __int_as_float(0x7f800000);  // +inf
    float vmax = 0.0f;
    const int stride = gridDim.x * blockDim.x;
    for (int i4 = blockIdx.x * blockDim.x + threadIdx.x; i4 < total4; i4 += stride) {
        const int4 it = reinterpret_cast<const int4*>(index_t)[i4];
        const int  h  = i4 >> 3;              // (i4*4) >> 5
        const int  row = index_h[h] * DCOLS;  // index_h cacheline-broadcast
        float v0 = 0.0f, v1 = 0.0f, v2 = 0.0f, v3 = 0.0f;
        if (it.x < DCOLS) v0 = dist[row + it.x];
        if (it.y < DCOLS) v1 = dist[row + it.y];
        if (it.z < DCOLS) v2 = dist[row + it.z];
        if (it.w < DCOLS) v3 = dist[row + it.w];
        vmin = fminf(fminf(fminf(vmin, v0), fminf(v1, v2)), v3);
        vmax = fmaxf(fmaxf(fmaxf(vmax, v0), fmaxf(v1, v2)), v3);
    }
    // wave-64 shuffle reduce
    #pragma unroll
    for (int off = 32; off > 0; off >>= 1) {
        vmin = fminf(vmin, __shfl_down(vmin, off, 64));
        vmax = fmaxf(vmax, __shfl_down(vmax, off, 64));
    }
    __shared__ float smin[4], smax[4];
    const int lane = threadIdx.x & 63;
    const int wave = threadIdx.x >> 6;
    if (lane == 0) { smin[wave] = vmin; smax[wave] = vmax; }
    __syncthreads();
    if (threadIdx.x == 0) {
        float m = smin[0], M = smax[0];
        #pragma unroll
        for (int k = 1; k < 4; ++k) { m = fminf(m, smin[k]); M = fmaxf(M, smax[k]); }
        atomicMin(ws,             __float_as_uint(-m));
        atomicMax((int*)(ws + 1), __float_as_int(M));
    }
}

// ---------------------------------------------------------------------------
// Kernel 2: 8 rows per 256-thread block.
//  - All 256 threads perform one gather each (8 rows x 32 cols) -> 2x the
//    in-flight scattered loads per block vs the 128-loader version.
//  - Each thread stores 6 float4s; the block's 1536 float4s (24 KB) are
//    perfectly contiguous starting at out + h0*768.
//  - Output is write-once: nontemporal stores (measured equal-or-better than
//    cached stores; round-1 A/B).
__global__ __launch_bounds__(256) void fill_kernel(
    const float* __restrict__ dist,
    const float* __restrict__ angle,
    const int*   __restrict__ idx_t,
    const int*   __restrict__ index_t,
    const int*   __restrict__ index_h,
    const unsigned* __restrict__ ws,
    float*       __restrict__ out,
    int H)
{
    const int h0  = blockIdx.x * ROWS_PER_BLOCK;
    const int tid = threadIdx.x;

    __shared__ int   s_idx[ROWS_PER_BLOCK][WCOLS];
    __shared__ float s_dist[ROWS_PER_BLOCK][WCOLS];
    __shared__ float s_angle[ROWS_PER_BLOCK][WCOLS];

    {
        const float dmin = -__uint_as_float(ws[0]);
        const float dmax =  __uint_as_float(ws[1]);
        const float inv  = 1.0f / (dmax - dmin);
        const int r = tid >> 5;
        const int c = tid & 31;
        const int h = h0 + r;
        if (h < H) {
            const int it = index_t[h * WCOLS + c];
            s_idx[r][c] = idx_t[h * WCOLS + c];
            float dv = 0.0f, av = 0.0f;
            if (it < DCOLS) {
                const int base = index_h[h] * DCOLS;
                dv = dist[base + it];
                av = angle[base + it];
            }
            s_dist[r][c]  = (dv - dmin) * inv;
            s_angle[r][c] = av;
        }
    }
    __syncthreads();

    const bool full = (h0 + ROWS_PER_BLOCK) <= H;
    #pragma unroll
    for (int m = 0; m < 6; ++m) {
        const int t    = m * 256 + tid;       // 0..1535 across the block
        const int row  = t / 192;             // const-div -> mul/shift
        const int col4 = t - row * 192;
        const int j0   = col4 * 4;
        vfloat4 v4;
        #pragma unroll
        for (int k = 0; k < 4; ++k) {
            const int j = j0 + k;
            float v;
            if (j < ONEHOT_COLS) {
                const int w = j / NUM_CLASSES;
                const int c = j - w * NUM_CLASSES;
                v = (s_idx[row][w] == c) ? 1.0f : 0.0f;
            } else if (j < ONEHOT_COLS + WCOLS) {
                v = s_dist[row][j - ONEHOT_COLS];
            } else {
                v = s_angle[row][j - (ONEHOT_COLS + WCOLS)];
            }
            v4[k] = v;
        }
        if (full) {
            vfloat4* o = reinterpret_cast<vfloat4*>(out + (size_t)h0 * OUT_COLS);
            __builtin_nontemporal_store(v4, o + t);
        } else if (h0 + row < H) {
            vfloat4* o = reinterpret_cast<vfloat4*>(out + (size_t)(h0 + row) * OUT_COLS);
            __builtin_nontemporal_store(v4, o + col4);
        }
    }
}

// ---------------------------------------------------------------------------
extern "C" void kernel_launch(void* const* d_in, const int* in_sizes, int n_in,
                              void* d_out, int out_size, void* d_ws, size_t ws_size,
                              hipStream_t stream) {
    const float* dist    = (const float*)d_in[0];
    const float* angle   = (const float*)d_in[1];
    const int*   idx_t   = (const int*)d_in[2];
    const int*   index_t = (const int*)d_in[3];
    const int*   index_h = (const int*)d_in[4];
    float*       out     = (float*)d_out;
    unsigned*    ws      = (unsigned*)d_ws;

    const int H      = in_sizes[4];           // index_h has H elements
    const int total4 = (H * WCOLS) / 4;       // H*32 always divisible by 4

    // Seed both min/max accumulators with 0xFFFFFFFF (see encoding above).
    (void)hipMemsetAsync(ws, 0xFF, 8, stream);

    hipLaunchKernelGGL(minmax_kernel, dim3(1024), dim3(256), 0, stream,
                       dist, index_t, index_h, ws, total4);

    const int fill_blocks = (H + ROWS_PER_BLOCK - 1) / ROWS_PER_BLOCK;
    hipLaunchKernelGGL(fill_kernel, dim3(fill_blocks), dim3(256), 0, stream,
                       dist, angle, idx_t, index_t, index_h, ws, out, H);
}